// Round 11
// baseline (552.691 us; speedup 1.0000x reference)
//
#include <hip/hip_runtime.h>
#include <math.h>

// ---------------- problem constants ----------------
#define BATCH 2
#define CCH   128
#define H1    96
#define W1    96
#define H2    48
#define W2    48
#define LP    2304   // H2*W2
#define K1    1152   // CCH*9
#define M2    2048   // CCH*16

typedef __attribute__((ext_vector_type(8))) short short8;
typedef __attribute__((ext_vector_type(4))) float f32x4;
typedef __attribute__((ext_vector_type(4))) short short4v;

// bf16 helpers (RN-even)
__device__ __forceinline__ unsigned short f2bf(float x) {
    unsigned u = __float_as_uint(x);
    return (unsigned short)((u + 0x7fffu + ((u >> 16) & 1u)) >> 16);
}
__device__ __forceinline__ float bf2f(unsigned short h) {
    return __uint_as_float(((unsigned)h) << 16);
}

// ---------------- bilinear resize (exact jnp.linspace replication) ----------
__device__ __forceinline__ float lin_coord(int i) {
    if (i == 47) return 95.0f;
    return __fmul_rn(95.0f, __fdiv_rn((float)i, 47.0f));
}

__global__ void resize_masks(const float* __restrict__ mask,
                             const float* __restrict__ mask_all,
                             float* __restrict__ ms, float* __restrict__ ma) {
    int idx = blockIdx.x * 256 + threadIdx.x;
    if (idx >= BATCH * LP) return;
    int b = idx / LP, r = idx % LP;
    int i = r / W2, j = r % W2;
    float ys = lin_coord(i), xs = lin_coord(j);
    int y0 = (int)ys; int y1 = min(y0 + 1, 95);
    int x0 = (int)xs; int x1 = min(x0 + 1, 95);
    float wy = __fsub_rn(ys, (float)y0);
    float wx = __fsub_rn(xs, (float)x0);
    float wy1 = __fsub_rn(1.0f, wy), wx1 = __fsub_rn(1.0f, wx);
    const float* mb = mask + b * H1 * W1;
    float t0 = __fadd_rn(__fmul_rn(mb[y0*W1+x0], wy1), __fmul_rn(mb[y1*W1+x0], wy));
    float t1 = __fadd_rn(__fmul_rn(mb[y0*W1+x1], wy1), __fmul_rn(mb[y1*W1+x1], wy));
    ms[idx] = __fadd_rn(__fmul_rn(t0, wx1), __fmul_rn(t1, wx));
    const float* ab = mask_all + b * H1 * W1;
    t0 = __fadd_rn(__fmul_rn(ab[y0*W1+x0], wy1), __fmul_rn(ab[y1*W1+x0], wy));
    t1 = __fadd_rn(__fmul_rn(ab[y0*W1+x1], wy1), __fmul_rn(ab[y1*W1+x1], wy));
    ma[idx] = __fadd_rn(__fmul_rn(t0, wx1), __fmul_rn(t1, wx));
}

__global__ void compute_mm(const float* __restrict__ ms, float* __restrict__ mm) {
    int idx = blockIdx.x * 256 + threadIdx.x;
    if (idx >= BATCH * LP) return;
    int b = idx / LP, r = idx % LP;
    int ci = r / W2, cj = r % W2;
    const float* m = ms + b * LP;
    bool any = false;
    #pragma unroll
    for (int di = -1; di <= 1; ++di)
        #pragma unroll
        for (int dj = -1; dj <= 1; ++dj) {
            int y = ci + di, x = cj + dj;
            if ((unsigned)y < H2 && (unsigned)x < W2)
                any = any || (m[y*W2 + x] > 0.0f);
        }
    mm[idx] = any ? 0.0f : 1.0f;
}

// im2col of x2 into TRIPLE-split bf16 padded tiles: [by][kt][r=128][40 shorts]
__global__ void im2col_split3(const float* __restrict__ x2,
                              short* __restrict__ A0, short* __restrict__ A1,
                              short* __restrict__ A2,
                              size_t sIn, size_t sOut) {
    int idx = blockIdx.x * 256 + threadIdx.x;      // p*K1 + k
    int z = blockIdx.y;
    int p = idx / K1, k = idx - p * K1;
    int ch = k / 9, t = k - ch * 9, dy = t / 3, dx = t - dy * 3;
    int i = p / W2, j = p - i * W2;
    int y = i + dy - 1, x = j + dx - 1;
    float v = 0.0f;
    if ((unsigned)y < H2 && (unsigned)x < W2) v = x2[z*sIn + ch*LP + y*W2 + x];
    unsigned short h0 = f2bf(v);
    float r1 = v - bf2f(h0);
    unsigned short h1 = f2bf(r1);
    unsigned short h2 = f2bf(r1 - bf2f(h1));
    size_t off = ((size_t)((p >> 7) * 36 + (k >> 5)) * 128 + (p & 127)) * 40 + (k & 31);
    A0[z*sOut + off] = (short)h0;
    A1[z*sOut + off] = (short)h1;
    A2[z*sOut + off] = (short)h2;
}

// raw_w rows into 2-split bf16 padded tiles: [mby][ckt][r=128][40 shorts]
__global__ void rwt_split(const float* __restrict__ x1,
                          short* __restrict__ Rh, short* __restrict__ Rl,
                          size_t sIn, size_t sOut) {
    int idx = blockIdx.x * 256 + threadIdx.x;      // m*LP + c
    int z = blockIdx.y;
    int m = idx / LP, c = idx - m * LP;
    int ci = c / W2, cj = c - ci * W2;
    int ch = m >> 4, kk = m & 15, ky = kk >> 2, kx = kk & 3;
    int y = 2*ci + ky - 1, x = 2*cj + kx - 1;
    float v = 0.0f;
    if ((unsigned)y < H1 && (unsigned)x < W1) v = x1[z*sIn + (size_t)ch*H1*W1 + y*W1 + x];
    unsigned short h = f2bf(v);
    unsigned short l = f2bf(v - bf2f(h));
    size_t off = ((size_t)((m >> 7) * 72 + (c >> 5)) * 128 + (m & 127)) * 40 + (c & 31);
    Rh[z*sOut + off] = (short)h;
    Rl[z*sOut + off] = (short)l;
}

#define WAITV(n) asm volatile("s_waitcnt vmcnt(" #n ")" ::: "memory")

// ---------------- S-split bf16 MFMA GEMM, counted-vmcnt pipeline ----------
// C[m][n] = sum_k A[m][k]*B[n][k], A = sum A_s, B = sum B_s; products i+j<S.
// Tiles: [tile][kt][128][40 shorts]. 4 waves (2x2), wave 64x64, 16x16x32 frags.
// Pipeline per kt: STAGE(kt+1 -> buf^1) -> s_waitcnt vmcnt(own kt+1 issues)
// -> raw s_barrier (publish tile kt) -> ds_read+MFMA -> raw s_barrier.
// Prefetched loads stay in flight across compute (T4); no vmcnt(0) drain.
// SYM: triangular grid (171 slots), mirror-store transpose; XCD-chunked order.
// !SYM: 288-slot grid remapped so each XCD (slot%8) owns a 9x4 tile region.
template <int S, bool SYM>
__global__ __launch_bounds__(256) void gemm_mfma_split(
    const short* __restrict__ A0, const short* __restrict__ A1,
    const short* __restrict__ A2,
    const short* __restrict__ B0, const short* __restrict__ B1,
    const short* __restrict__ B2,
    float* __restrict__ Cb, const int KT, const int N,
    const size_t sA, const size_t sB, const size_t sC)
{
    __shared__ f32x4 lds4[4 * S * 640];            // 2 buffers x 2S x 10240 B
    char* lds = (char*)lds4;
    constexpr int BUFB = S * 20480;                // bytes per buffer
    const int bz = blockIdx.z;
    int bx, by;
    if constexpr (SYM) {
        // slot -> XCD-chunked triangular tile (rows grouped per XCD)
        const int s = blockIdx.x;                  // 0..170
        const int k = s & 7, j = s >> 3;
        int t = 21 * k + min(k, 3) + j;
        int r = 0, rem = t;
        #pragma unroll
        for (int it = 0; it < 17; ++it) {
            int n = 18 - it;
            if (rem >= n) { rem -= n; ++r; } else break;
        }
        by = r; bx = by + rem;
    } else {
        // slot -> 9x4 region per XCD: grid 18x16 = 288 slots
        const int s = blockIdx.x;                  // 0..287
        const int k = s & 7, j = s >> 3;           // j in 0..35
        bx = (k & 1) * 9 + (j % 9);
        by = (k >> 1) * 4 + (j / 9);
    }
    const int tid = threadIdx.x, lane = tid & 63, w = tid >> 6;
    const int wm = w >> 1, wn = w & 1;
    const size_t tA = (size_t)bz * sA + (size_t)by * KT * 5120;
    const size_t tB = (size_t)bz * sB + (size_t)bx * KT * 5120;

    // staging assignment: arrays 0..S-1 = A splits, S..2S-1 = B splits
    const short* s1; int d1off;
    const short* s2 = nullptr; int d2off = 0;
    if constexpr (S == 2) {
        s1 = (w == 0 ? A0 : w == 1 ? A1 : w == 2 ? B0 : B1) + ((w < 2) ? tA : tB);
        d1off = w * 10240;
    } else {
        s1 = (w == 0 ? A0 : w == 1 ? A1 : w == 2 ? A2 : B0) + ((w < 3) ? tA : tB);
        d1off = w * 10240;
        if (w < 2) { s2 = (w == 0 ? B1 : B2) + tB; d2off = (4 + w) * 10240; }
    }

    f32x4 acc[4][4];
    #pragma unroll
    for (int i = 0; i < 4; ++i)
        #pragma unroll
        for (int j = 0; j < 4; ++j) acc[i][j] = (f32x4){0.f, 0.f, 0.f, 0.f};

    const int fr = lane & 15;
    const int fkb = (lane >> 4) * 16;

    auto STAGE = [&](int kt, int buf) {
        char* dbase = lds + buf * BUFB;
        const char* g1 = (const char*)(s1 + (size_t)kt * 5120);
        #pragma unroll
        for (int u = 0; u < 10; ++u)
            __builtin_amdgcn_global_load_lds(
                (const __attribute__((address_space(1))) unsigned int*)(g1 + u*1024 + lane*16),
                (__attribute__((address_space(3))) unsigned int*)(dbase + d1off + u*1024),
                16, 0, 0);
        if constexpr (S == 3) {
            if (w < 2) {
                const char* g2 = (const char*)(s2 + (size_t)kt * 5120);
                #pragma unroll
                for (int u = 0; u < 10; ++u)
                    __builtin_amdgcn_global_load_lds(
                        (const __attribute__((address_space(1))) unsigned int*)(g2 + u*1024 + lane*16),
                        (__attribute__((address_space(3))) unsigned int*)(dbase + d2off + u*1024),
                        16, 0, 0);
            }
        }
    };

    STAGE(0, 0);
    for (int kt = 0; kt < KT; ++kt) {
        const int cur = kt & 1;
        const bool more = (kt + 1 < KT);
        if (more) STAGE(kt + 1, cur ^ 1);
        // wait for OWN kt loads: outstanding <= what we just issued for kt+1
        if (more) {
            if constexpr (S == 3) {
                if (w < 2) { WAITV(20); } else { WAITV(10); }
            } else {
                WAITV(10);
            }
        } else {
            WAITV(0);
        }
        __builtin_amdgcn_sched_barrier(0);
        __builtin_amdgcn_s_barrier();              // publish tile kt
        const char* cbase = lds + cur * BUFB;

        short8 bf[S][4];
        #pragma unroll
        for (int s = 0; s < S; ++s)
            #pragma unroll
            for (int ni = 0; ni < 4; ++ni) {
                const int r = wn*64 + ni*16 + fr;
                bf[s][ni] = *(const short8*)(cbase + (S + s)*10240 + r*80 + fkb);
            }
        #pragma unroll
        for (int mi = 0; mi < 4; ++mi) {
            const int r = wm*64 + mi*16 + fr;
            short8 af[S];
            #pragma unroll
            for (int s = 0; s < S; ++s)
                af[s] = *(const short8*)(cbase + s*10240 + r*80 + fkb);
            #pragma unroll
            for (int ni = 0; ni < 4; ++ni) {
                acc[mi][ni] = __builtin_amdgcn_mfma_f32_16x16x32_bf16(af[0], bf[0][ni], acc[mi][ni], 0, 0, 0);
                acc[mi][ni] = __builtin_amdgcn_mfma_f32_16x16x32_bf16(af[0], bf[1][ni], acc[mi][ni], 0, 0, 0);
                acc[mi][ni] = __builtin_amdgcn_mfma_f32_16x16x32_bf16(af[1], bf[0][ni], acc[mi][ni], 0, 0, 0);
                if constexpr (S == 3) {
                    acc[mi][ni] = __builtin_amdgcn_mfma_f32_16x16x32_bf16(af[0], bf[2][ni], acc[mi][ni], 0, 0, 0);
                    acc[mi][ni] = __builtin_amdgcn_mfma_f32_16x16x32_bf16(af[1], bf[1][ni], acc[mi][ni], 0, 0, 0);
                    acc[mi][ni] = __builtin_amdgcn_mfma_f32_16x16x32_bf16(af[2], bf[0][ni], acc[mi][ni], 0, 0, 0);
                }
            }
        }
        __builtin_amdgcn_s_barrier();              // all reads of buf done
    }
    // epilogue: D col=lane&15, row=(lane>>4)*4+reg  [verified m89 mapping]
    float* C = Cb + (size_t)bz * sC;
    const int cr = (lane >> 4) * 4, cc = lane & 15;
    const int row0 = by*128 + wm*64, col0 = bx*128 + wn*64;
    #pragma unroll
    for (int mi = 0; mi < 4; ++mi)
        #pragma unroll
        for (int ni = 0; ni < 4; ++ni) {
            float* cp = C + (size_t)(row0 + mi*16 + cr) * N + col0 + ni*16 + cc;
            #pragma unroll
            for (int rg = 0; rg < 4; ++rg)
                cp[(size_t)rg * N] = acc[mi][ni][rg];
        }
    if constexpr (SYM) {
        if (bx != by) {
            // mirror: C[n][m]; m = row0+mi*16+cr+rg is contiguous in rg -> float4
            #pragma unroll
            for (int mi = 0; mi < 4; ++mi)
                #pragma unroll
                for (int ni = 0; ni < 4; ++ni) {
                    const int n = col0 + ni*16 + cc;
                    float* mp = C + (size_t)n * N + row0 + mi*16 + cr;
                    *(float4*)mp = make_float4(acc[mi][ni][0], acc[mi][ni][1],
                                               acc[mi][ni][2], acc[mi][ni][3]);
                }
        }
    }
}

// rcp[z][c] = 1 / max(sqrt(U[c][c]), 1e-4)
__global__ void diag_rcp(const float* __restrict__ U, float* __restrict__ rcp,
                         size_t sU) {
    int c = blockIdx.x * 256 + threadIdx.x;
    int z = blockIdx.y;
    if (c >= LP) return;
    rcp[z*LP + c] = 1.0f / fmaxf(sqrtf(U[(size_t)z*sU + (size_t)c * (LP + 1)]), 1e-4f);
}

// Row softmax over U[p][*] fused with masking, boost, clip, bf16 2-split.
// One wave per row p; writes V tiles [pby][ckt][r][40].
__global__ __launch_bounds__(256) void softmax_split(
    const float* __restrict__ Ub, const float* __restrict__ rcpb,
    const float* __restrict__ mmb, const float* __restrict__ mab,
    short* __restrict__ Vhi, short* __restrict__ Vlo,
    size_t sU, size_t sV)
{
    const int z = blockIdx.y;
    const int wid = threadIdx.x >> 6, lane = threadIdx.x & 63;
    const int p = blockIdx.x * 4 + wid;
    const float* U = Ub + (size_t)z * sU + (size_t)p * LP;
    const float* rcp = rcpb + z * LP;
    const float* mm = mmb + (size_t)z * LP;
    const float maP = mab[(size_t)z * LP + p];
    const float maS = maP * 10.0f;
    float t[9][4], mv[9][4];
    float mx = -INFINITY;
    #pragma unroll
    for (int i = 0; i < 9; ++i) {
        const int c = i * 256 + lane * 4;
        float4 u4 = *(const float4*)(U + c);
        float4 r4 = *(const float4*)(rcp + c);
        float4 m4 = *(const float4*)(mm + c);
        t[i][0] = u4.x * r4.x * m4.x * maS;  mv[i][0] = m4.x;
        t[i][1] = u4.y * r4.y * m4.y * maS;  mv[i][1] = m4.y;
        t[i][2] = u4.z * r4.z * m4.z * maS;  mv[i][2] = m4.z;
        t[i][3] = u4.w * r4.w * m4.w * maS;  mv[i][3] = m4.w;
        #pragma unroll
        for (int jj = 0; jj < 4; ++jj) mx = fmaxf(mx, t[i][jj]);
    }
    #pragma unroll
    for (int off = 32; off > 0; off >>= 1) mx = fmaxf(mx, __shfl_xor(mx, off, 64));
    float sm = 0.0f;
    #pragma unroll
    for (int i = 0; i < 9; ++i)
        #pragma unroll
        for (int jj = 0; jj < 4; ++jj) sm += __expf(t[i][jj] - mx);
    #pragma unroll
    for (int off = 32; off > 0; off >>= 1) sm += __shfl_xor(sm, off, 64);
    const float rS = 1.0f / sm;
    const int pi = p / W2, pj = p - pi * W2;
    const int pby = p >> 7, pr = p & 127;
    #pragma unroll
    for (int i = 0; i < 9; ++i) {
        const int c = i * 256 + lane * 4;
        short4v h4, l4;
        #pragma unroll
        for (int jj = 0; jj < 4; ++jj) {
            int cc = c + jj;
            float r = __expf(t[i][jj] - mx) * rS;
            int ci = cc / W2, cj = cc - ci * W2;
            if (abs(ci - pi) + abs(cj - pj) == 1) r = r + r * 0.5f;
            r = (r * mv[i][jj]) * maP;
            r = fmaxf(r, 1e-8f);
            unsigned short h = f2bf(r);
            unsigned short l = f2bf(r - bf2f(h));
            h4[jj] = (short)h; l4[jj] = (short)l;
        }
        size_t voff = ((size_t)(pby * 72 + (c >> 5)) * 128 + pr) * 40 + (c & 31);
        *(short4v*)(Vhi + (size_t)z * sV + voff) = h4;
        *(short4v*)(Vlo + (size_t)z * sV + voff) = l4;
    }
}

// y[z][ch][yy][xx] = 0.25 * sum over valid (ky,kx) of Z[(ch,ky,kx)][i*48+j]
__global__ void scatter_y(const float* __restrict__ Zb, float* __restrict__ yb,
                          size_t sZ, size_t sY) {
    int idx = blockIdx.x * 256 + threadIdx.x;
    int z = blockIdx.y;
    const float* Z = Zb + (size_t)z * sZ;
    int ch = idx / (H1*W1), r = idx % (H1*W1);
    int yy = r / W1, xx = r % W1;
    float s = 0.0f;
    #pragma unroll
    for (int ky = 0; ky < 4; ++ky) {
        int ny = yy + 1 - ky;
        if (ny & 1) continue;
        int i = ny >> 1;
        if ((unsigned)i >= H2) continue;
        #pragma unroll
        for (int kx = 0; kx < 4; ++kx) {
            int nx = xx + 1 - kx;
            if (nx & 1) continue;
            int j = nx >> 1;
            if ((unsigned)j >= W2) continue;
            s += Z[(size_t)(ch*16 + ky*4 + kx) * LP + i*W2 + j];
        }
    }
    yb[(size_t)z * sY + idx] = s * 0.25f;
}

// Dilated conv, IC-split 4x: block (bx = b*4*36 + g*36 + tile, by = ic chunk).
__global__ __launch_bounds__(256) void dilated_conv_part(
    const float* __restrict__ y, const float* __restrict__ w,
    float* __restrict__ part) {
    int bid = blockIdx.x;                 // b*4*36 + g*36 + tile
    int tile = bid % 36; int g = (bid / 36) % 4; int b = bid / 144;
    int c4 = blockIdx.y;                  // ic chunk: [c4*32, c4*32+32)
    int yy = (tile / 6) * 16 + (threadIdx.x >> 4);
    int xx = (tile % 6) * 16 + (threadIdx.x & 15);
    int rr = 1 << g;                      // RATES = 1,2,4,8
    const float* yb = y + ((size_t)b * CCH + c4 * 32) * (H1 * W1);
    const float* wg = w + g * 16 * CCH * 9 + c4 * 32 * 9;
    float acc[16] = {};
    #pragma unroll 2
    for (int ic = 0; ic < 32; ++ic) {
        const float* yc = yb + ic * (H1 * W1);
        #pragma unroll
        for (int t = 0; t < 9; ++t) {
            int sy = yy + rr * (t / 3 - 1), sx = xx + rr * (t % 3 - 1);
            float v = 0.0f;
            if ((unsigned)sy < H1 && (unsigned)sx < W1) v = yc[sy*W1 + sx];
            #pragma unroll
            for (int oc = 0; oc < 16; ++oc)
                acc[oc] = fmaf(v, wg[(oc*CCH + ic)*9 + t], acc[oc]);
        }
    }
    // part layout: [c4][b][oc64][9216]
    float* pb = part + (((size_t)c4 * BATCH + b) * 64 + g * 16) * (H1 * W1)
                     + yy * W1 + xx;
    #pragma unroll
    for (int oc = 0; oc < 16; ++oc)
        pb[(size_t)oc * (H1 * W1)] = acc[oc];
}

// out[b][oc64][pix] = relu(sum_c4 part[c4][b][oc64][pix] + bias[oc64])
__global__ void conv_reduce(const float* __restrict__ part,
                            const float* __restrict__ bias,
                            float* __restrict__ out) {
    int idx = blockIdx.x * 256 + threadIdx.x;     // [0, 2*64*9216)
    int pix = idx % (H1 * W1);
    int rest = idx / (H1 * W1);
    int oc64 = rest % 64, b = rest / 64;
    const size_t st = (size_t)BATCH * 64 * (H1 * W1);
    size_t o = ((size_t)b * 64 + oc64) * (H1 * W1) + pix;
    float s = part[o] + part[st + o] + part[2*st + o] + part[3*st + o];
    out[o] = fmaxf(s + bias[oc64], 0.0f);
}

extern "C" void kernel_launch(void* const* d_in, const int* in_sizes, int n_in,
                              void* d_out, int out_size, void* d_ws, size_t ws_size,
                              hipStream_t stream) {
    const float* x1       = (const float*)d_in[0];
    const float* x2       = (const float*)d_in[1];
    const float* mask     = (const float*)d_in[2];
    const float* mask_all = (const float*)d_in[3];
    const float* conv_w   = (const float*)d_in[4];
    const float* conv_b   = (const float*)d_in[5];

    // per-batch element counts
    const size_t EA = 3317760;   // shorts: 18*36*128*40
    const size_t ER = 5898240;   // shorts: 16*72*128*40
    const size_t EV = 6635520;   // shorts: 18*72*128*40
    const size_t FU = 5308416;   // floats: 2304*2304
    const size_t FZ = 4718592;   // floats: 2048*2304
    const size_t FY = 2359296;   // floats: both batches of Y

    struct Offs { size_t A0, A1, A2, U, Rhi, Rlo, Z, Vhi, Vlo, Y, MS, MA, MM, RCP, need; };
    auto mk = [&](int NZ) {
        Offs o;
        o.A0 = 0;
        o.A1 = o.A0 + (size_t)NZ * EA * 2;
        o.A2 = o.A1 + (size_t)NZ * EA * 2;
        o.U  = o.A2 + (size_t)NZ * EA * 2;
        size_t endA = o.U + (size_t)NZ * FU * 4;
        o.Rhi = 0;                               // reuses A/U region (dead by then)
        o.Rlo = o.Rhi + (size_t)NZ * ER * 2;
        o.Z   = o.Rlo + (size_t)NZ * ER * 2;
        size_t endR = o.Z + (size_t)NZ * FZ * 4;
        size_t r1 = endA > endR ? endA : endR;
        o.Vhi = r1;
        o.Vlo = o.Vhi + (size_t)NZ * EV * 2;
        o.Y   = o.Vlo + (size_t)NZ * EV * 2;
        o.MS  = o.Y + FY * 4;
        o.MA  = o.MS + 4608 * 4;
        o.MM  = o.MA + 4608 * 4;
        o.RCP = o.MM + 4608 * 4;
        o.need = o.RCP + 4608 * 4;
        return o;
    };
    Offs o2 = mk(2), o1 = mk(1);
    if (ws_size < o1.need) return;               // fail loudly
    const int NZ = (ws_size >= o2.need) ? 2 : 1;
    Offs o = (NZ == 2) ? o2 : o1;

    char* base = (char*)d_ws;
    short* A0  = (short*)(base + o.A0);
    short* A1  = (short*)(base + o.A1);
    short* A2  = (short*)(base + o.A2);
    float* U   = (float*)(base + o.U);
    short* Rhi = (short*)(base + o.Rhi);
    short* Rlo = (short*)(base + o.Rlo);
    float* Z   = (float*)(base + o.Z);
    short* Vhi = (short*)(base + o.Vhi);
    short* Vlo = (short*)(base + o.Vlo);
    float* Y   = (float*)(base + o.Y);
    float* MS  = (float*)(base + o.MS);
    float* MA  = (float*)(base + o.MA);
    float* MM  = (float*)(base + o.MM);
    float* RCP = (float*)(base + o.RCP);
    // conv partials alias region-1 (A/U/R/Z all dead after last scatter_y)
    float* PART = (float*)(base + 0);

    resize_masks<<<18, 256, 0, stream>>>(mask, mask_all, MS, MA);
    compute_mm<<<18, 256, 0, stream>>>(MS, MM);

    const size_t sX2 = (size_t)CCH * LP;
    const size_t sX1 = (size_t)CCH * H1 * W1;
    const size_t sYb = (size_t)CCH * H1 * W1;

    const int nIter = (NZ == 2) ? 1 : 2;
    for (int it = 0; it < nIter; ++it) {
        const int b0 = (NZ == 2) ? 0 : it;
        im2col_split3<<<dim3(10368, NZ), 256, 0, stream>>>(
            x2 + (size_t)b0 * sX2, A0, A1, A2, sX2, EA);
        gemm_mfma_split<3, true><<<dim3(171, 1, NZ), 256, 0, stream>>>(
            A0, A1, A2, A0, A1, A2, U, 36, LP, EA, EA, FU);
        diag_rcp<<<dim3(9, NZ), 256, 0, stream>>>(U, RCP, FU);
        softmax_split<<<dim3(576, NZ), 256, 0, stream>>>(
            U, RCP, MM + (size_t)b0 * LP, MA + (size_t)b0 * LP, Vhi, Vlo, FU, EV);
        rwt_split<<<dim3(18432, NZ), 256, 0, stream>>>(
            x1 + (size_t)b0 * sX1, Rhi, Rlo, sX1, ER);
        gemm_mfma_split<2, false><<<dim3(288, 1, NZ), 256, 0, stream>>>(
            Rhi, Rlo, nullptr, Vhi, Vlo, nullptr, Z, 72, LP, ER, EV, FZ);
        scatter_y<<<dim3(4608, NZ), 256, 0, stream>>>(
            Z, Y + (size_t)b0 * sYb, FZ, sYb);
    }
    dilated_conv_part<<<dim3(288, 4), 256, 0, stream>>>(Y, conv_w, PART);
    conv_reduce<<<4608, 256, 0, stream>>>(PART, conv_b, (float*)d_out);
}

// Round 12
// 449.289 us; speedup vs baseline: 1.2301x; 1.2301x over previous
//
#include <hip/hip_runtime.h>
#include <math.h>

// ---------------- problem constants ----------------
#define BATCH 2
#define CCH   128
#define H1    96
#define W1    96
#define H2    48
#define W2    48
#define LP    2304   // H2*W2
#define K1    1152   // CCH*9
#define M2    2048   // CCH*16

typedef __attribute__((ext_vector_type(8))) short short8;
typedef __attribute__((ext_vector_type(4))) float f32x4;
typedef __attribute__((ext_vector_type(4))) short short4v;

// bf16 helpers (RN-even)
__device__ __forceinline__ unsigned short f2bf(float x) {
    unsigned u = __float_as_uint(x);
    return (unsigned short)((u + 0x7fffu + ((u >> 16) & 1u)) >> 16);
}
__device__ __forceinline__ float bf2f(unsigned short h) {
    return __uint_as_float(((unsigned)h) << 16);
}

// ---------------- bilinear resize (exact jnp.linspace replication) ----------
__device__ __forceinline__ float lin_coord(int i) {
    if (i == 47) return 95.0f;
    return __fmul_rn(95.0f, __fdiv_rn((float)i, 47.0f));
}

__global__ void resize_masks(const float* __restrict__ mask,
                             const float* __restrict__ mask_all,
                             float* __restrict__ ms, float* __restrict__ ma) {
    int idx = blockIdx.x * 256 + threadIdx.x;
    if (idx >= BATCH * LP) return;
    int b = idx / LP, r = idx % LP;
    int i = r / W2, j = r % W2;
    float ys = lin_coord(i), xs = lin_coord(j);
    int y0 = (int)ys; int y1 = min(y0 + 1, 95);
    int x0 = (int)xs; int x1 = min(x0 + 1, 95);
    float wy = __fsub_rn(ys, (float)y0);
    float wx = __fsub_rn(xs, (float)x0);
    float wy1 = __fsub_rn(1.0f, wy), wx1 = __fsub_rn(1.0f, wx);
    const float* mb = mask + b * H1 * W1;
    float t0 = __fadd_rn(__fmul_rn(mb[y0*W1+x0], wy1), __fmul_rn(mb[y1*W1+x0], wy));
    float t1 = __fadd_rn(__fmul_rn(mb[y0*W1+x1], wy1), __fmul_rn(mb[y1*W1+x1], wy));
    ms[idx] = __fadd_rn(__fmul_rn(t0, wx1), __fmul_rn(t1, wx));
    const float* ab = mask_all + b * H1 * W1;
    t0 = __fadd_rn(__fmul_rn(ab[y0*W1+x0], wy1), __fmul_rn(ab[y1*W1+x0], wy));
    t1 = __fadd_rn(__fmul_rn(ab[y0*W1+x1], wy1), __fmul_rn(ab[y1*W1+x1], wy));
    ma[idx] = __fadd_rn(__fmul_rn(t0, wx1), __fmul_rn(t1, wx));
}

__global__ void compute_mm(const float* __restrict__ ms, float* __restrict__ mm) {
    int idx = blockIdx.x * 256 + threadIdx.x;
    if (idx >= BATCH * LP) return;
    int b = idx / LP, r = idx % LP;
    int ci = r / W2, cj = r % W2;
    const float* m = ms + b * LP;
    bool any = false;
    #pragma unroll
    for (int di = -1; di <= 1; ++di)
        #pragma unroll
        for (int dj = -1; dj <= 1; ++dj) {
            int y = ci + di, x = cj + dj;
            if ((unsigned)y < H2 && (unsigned)x < W2)
                any = any || (m[y*W2 + x] > 0.0f);
        }
    mm[idx] = any ? 0.0f : 1.0f;
}

// im2col of x2 into TRIPLE-split bf16 padded tiles: [by][kt][r=128][40 shorts]
__global__ void im2col_split3(const float* __restrict__ x2,
                              short* __restrict__ A0, short* __restrict__ A1,
                              short* __restrict__ A2,
                              size_t sIn, size_t sOut) {
    int idx = blockIdx.x * 256 + threadIdx.x;      // p*K1 + k
    int z = blockIdx.y;
    int p = idx / K1, k = idx - p * K1;
    int ch = k / 9, t = k - ch * 9, dy = t / 3, dx = t - dy * 3;
    int i = p / W2, j = p - i * W2;
    int y = i + dy - 1, x = j + dx - 1;
    float v = 0.0f;
    if ((unsigned)y < H2 && (unsigned)x < W2) v = x2[z*sIn + ch*LP + y*W2 + x];
    unsigned short h0 = f2bf(v);
    float r1 = v - bf2f(h0);
    unsigned short h1 = f2bf(r1);
    unsigned short h2 = f2bf(r1 - bf2f(h1));
    size_t off = ((size_t)((p >> 7) * 36 + (k >> 5)) * 128 + (p & 127)) * 40 + (k & 31);
    A0[z*sOut + off] = (short)h0;
    A1[z*sOut + off] = (short)h1;
    A2[z*sOut + off] = (short)h2;
}

// raw_w rows into SINGLE bf16 padded tiles: [mby][ckt][r=128][40 shorts]
__global__ void rwt_bf16(const float* __restrict__ x1,
                         short* __restrict__ Rh,
                         size_t sIn, size_t sOut) {
    int idx = blockIdx.x * 256 + threadIdx.x;      // m*LP + c
    int z = blockIdx.y;
    int m = idx / LP, c = idx - m * LP;
    int ci = c / W2, cj = c - ci * W2;
    int ch = m >> 4, kk = m & 15, ky = kk >> 2, kx = kk & 3;
    int y = 2*ci + ky - 1, x = 2*cj + kx - 1;
    float v = 0.0f;
    if ((unsigned)y < H1 && (unsigned)x < W1) v = x1[z*sIn + (size_t)ch*H1*W1 + y*W1 + x];
    size_t off = ((size_t)((m >> 7) * 72 + (c >> 5)) * 128 + (m & 127)) * 40 + (c & 31);
    Rh[z*sOut + off] = (short)f2bf(v);
}

// ---------------- GEMM1: triple-split symmetric Gram, 6 products ----------
// U[m][n] = sum_k A[m][k]*A[n][k] with A = A0+A1+A2, products i+j<3.
// Triangular grid (171 slots, XCD-chunked), mirror-store transpose.
// Single LDS buffer, 2 barriers/kt (r9 structure - measured best).
// Staging balanced: 15 chunks per wave (was 20/20/10/10).
__global__ __launch_bounds__(256) void gemm1_sym3(
    const short* __restrict__ A0, const short* __restrict__ A1,
    const short* __restrict__ A2,
    float* __restrict__ Cb, const int KT, const int N,
    const size_t sA, const size_t sC)
{
    __shared__ f32x4 lds4[6 * 640];                // 61440 B
    char* lds = (char*)lds4;
    const int bz = blockIdx.z;
    int bx, by;
    {   // slot -> XCD-chunked triangular tile
        const int s = blockIdx.x;                  // 0..170
        const int k = s & 7, j = s >> 3;
        int t = 21 * k + min(k, 3) + j;
        int r = 0, rem = t;
        #pragma unroll
        for (int it = 0; it < 17; ++it) {
            int n = 18 - it;
            if (rem >= n) { rem -= n; ++r; } else break;
        }
        by = r; bx = by + rem;
    }
    const int tid = threadIdx.x, lane = tid & 63, w = tid >> 6;
    const int wm = w >> 1, wn = w & 1;
    const size_t tA = (size_t)bz * sA + (size_t)by * KT * 5120;
    const size_t tB = (size_t)bz * sA + (size_t)bx * KT * 5120;

    // balanced staging: wave w -> full array w (10 chunks) + half array (5)
    // arrays: 0=A0@by 1=A1@by 2=A2@by 3=A0@bx 4=A1@bx 5=A2@bx
    const short* s1 = (w == 0) ? A0 + tA : (w == 1) ? A1 + tA
                    : (w == 2) ? A2 + tA : A0 + tB;
    const int d1 = w * 10240;
    const short* s2 = ((w < 2) ? A1 : A2) + tB;
    const int d2 = ((w < 2) ? 4 : 5) * 10240;
    const int u2lo = (w & 1) * 5;

    f32x4 acc[4][4];
    #pragma unroll
    for (int i = 0; i < 4; ++i)
        #pragma unroll
        for (int j = 0; j < 4; ++j) acc[i][j] = (f32x4){0.f, 0.f, 0.f, 0.f};

    const int fr = lane & 15;
    const int fkb = (lane >> 4) * 16;

    for (int kt = 0; kt < KT; ++kt) {
        const char* g1 = (const char*)(s1 + (size_t)kt * 5120);
        #pragma unroll
        for (int u = 0; u < 10; ++u)
            __builtin_amdgcn_global_load_lds(
                (const __attribute__((address_space(1))) unsigned int*)(g1 + u*1024 + lane*16),
                (__attribute__((address_space(3))) unsigned int*)(lds + d1 + u*1024),
                16, 0, 0);
        const char* g2 = (const char*)(s2 + (size_t)kt * 5120);
        #pragma unroll
        for (int u = 0; u < 5; ++u)
            __builtin_amdgcn_global_load_lds(
                (const __attribute__((address_space(1))) unsigned int*)(g2 + (u2lo+u)*1024 + lane*16),
                (__attribute__((address_space(3))) unsigned int*)(lds + d2 + (u2lo+u)*1024),
                16, 0, 0);
        __syncthreads();

        short8 bf[3][4];
        #pragma unroll
        for (int s = 0; s < 3; ++s)
            #pragma unroll
            for (int ni = 0; ni < 4; ++ni) {
                const int r = wn*64 + ni*16 + fr;
                bf[s][ni] = *(const short8*)(lds + (3 + s)*10240 + r*80 + fkb);
            }
        #pragma unroll
        for (int mi = 0; mi < 4; ++mi) {
            const int r = wm*64 + mi*16 + fr;
            short8 af[3];
            #pragma unroll
            for (int s = 0; s < 3; ++s)
                af[s] = *(const short8*)(lds + s*10240 + r*80 + fkb);
            #pragma unroll
            for (int ni = 0; ni < 4; ++ni) {
                acc[mi][ni] = __builtin_amdgcn_mfma_f32_16x16x32_bf16(af[0], bf[0][ni], acc[mi][ni], 0, 0, 0);
                acc[mi][ni] = __builtin_amdgcn_mfma_f32_16x16x32_bf16(af[0], bf[1][ni], acc[mi][ni], 0, 0, 0);
                acc[mi][ni] = __builtin_amdgcn_mfma_f32_16x16x32_bf16(af[1], bf[0][ni], acc[mi][ni], 0, 0, 0);
                acc[mi][ni] = __builtin_amdgcn_mfma_f32_16x16x32_bf16(af[0], bf[2][ni], acc[mi][ni], 0, 0, 0);
                acc[mi][ni] = __builtin_amdgcn_mfma_f32_16x16x32_bf16(af[1], bf[1][ni], acc[mi][ni], 0, 0, 0);
                acc[mi][ni] = __builtin_amdgcn_mfma_f32_16x16x32_bf16(af[2], bf[0][ni], acc[mi][ni], 0, 0, 0);
            }
        }
        __syncthreads();
    }
    // epilogue: D col=lane&15, row=(lane>>4)*4+reg  [verified m89 mapping]
    float* C = Cb + (size_t)bz * sC;
    const int cr = (lane >> 4) * 4, cc = lane & 15;
    const int row0 = by*128 + wm*64, col0 = bx*128 + wn*64;
    #pragma unroll
    for (int mi = 0; mi < 4; ++mi)
        #pragma unroll
        for (int ni = 0; ni < 4; ++ni) {
            float* cp = C + (size_t)(row0 + mi*16 + cr) * N + col0 + ni*16 + cc;
            #pragma unroll
            for (int rg = 0; rg < 4; ++rg)
                cp[(size_t)rg * N] = acc[mi][ni][rg];
        }
    if (bx != by) {
        #pragma unroll
        for (int mi = 0; mi < 4; ++mi)
            #pragma unroll
            for (int ni = 0; ni < 4; ++ni) {
                const int n = col0 + ni*16 + cc;
                float* mp = C + (size_t)n * N + row0 + mi*16 + cr;
                *(float4*)mp = make_float4(acc[mi][ni][0], acc[mi][ni][1],
                                           acc[mi][ni][2], acc[mi][ni][3]);
            }
    }
}

// ---------------- GEMM2: plain bf16, 1 product ----------
// Z[m][n] = sum_k Rh[m][k]*Vh[n][k].  LDS 20 KB, high occupancy.
// 288-slot grid, XCD 9x4 regions. r9 structure.
__global__ __launch_bounds__(256) void gemm2_bf16(
    const short* __restrict__ Rh, const short* __restrict__ Vh,
    float* __restrict__ Cb, const int KT, const int N,
    const size_t sA, const size_t sB, const size_t sC)
{
    __shared__ f32x4 lds4[2 * 640];                // 20480 B
    char* lds = (char*)lds4;
    const int bz = blockIdx.z;
    int bx, by;
    {   // slot -> 9x4 region per XCD: grid 18x16 = 288 slots
        const int s = blockIdx.x;
        const int k = s & 7, j = s >> 3;
        bx = (k & 1) * 9 + (j % 9);
        by = (k >> 1) * 4 + (j / 9);
    }
    const int tid = threadIdx.x, lane = tid & 63, w = tid >> 6;
    const int wm = w >> 1, wn = w & 1;
    const size_t tA = (size_t)bz * sA + (size_t)by * KT * 5120;
    const size_t tB = (size_t)bz * sB + (size_t)bx * KT * 5120;

    // staging: 20 chunks over 4 waves (5 each)
    const short* s1 = (w < 2) ? Rh + tA : Vh + tB;
    const int d1 = (w < 2) ? 0 : 10240;
    const int ulo = (w & 1) * 5;

    f32x4 acc[4][4];
    #pragma unroll
    for (int i = 0; i < 4; ++i)
        #pragma unroll
        for (int j = 0; j < 4; ++j) acc[i][j] = (f32x4){0.f, 0.f, 0.f, 0.f};

    const int fr = lane & 15;
    const int fkb = (lane >> 4) * 16;

    for (int kt = 0; kt < KT; ++kt) {
        const char* g1 = (const char*)(s1 + (size_t)kt * 5120);
        #pragma unroll
        for (int u = 0; u < 5; ++u)
            __builtin_amdgcn_global_load_lds(
                (const __attribute__((address_space(1))) unsigned int*)(g1 + (ulo+u)*1024 + lane*16),
                (__attribute__((address_space(3))) unsigned int*)(lds + d1 + (ulo+u)*1024),
                16, 0, 0);
        __syncthreads();

        short8 bf[4];
        #pragma unroll
        for (int ni = 0; ni < 4; ++ni) {
            const int r = wn*64 + ni*16 + fr;
            bf[ni] = *(const short8*)(lds + 10240 + r*80 + fkb);
        }
        #pragma unroll
        for (int mi = 0; mi < 4; ++mi) {
            const int r = wm*64 + mi*16 + fr;
            short8 af = *(const short8*)(lds + r*80 + fkb);
            #pragma unroll
            for (int ni = 0; ni < 4; ++ni)
                acc[mi][ni] = __builtin_amdgcn_mfma_f32_16x16x32_bf16(af, bf[ni], acc[mi][ni], 0, 0, 0);
        }
        __syncthreads();
    }
    float* C = Cb + (size_t)bz * sC;
    const int cr = (lane >> 4) * 4, cc = lane & 15;
    const int row0 = by*128 + wm*64, col0 = bx*128 + wn*64;
    #pragma unroll
    for (int mi = 0; mi < 4; ++mi)
        #pragma unroll
        for (int ni = 0; ni < 4; ++ni) {
            float* cp = C + (size_t)(row0 + mi*16 + cr) * N + col0 + ni*16 + cc;
            #pragma unroll
            for (int rg = 0; rg < 4; ++rg)
                cp[(size_t)rg * N] = acc[mi][ni][rg];
        }
}

// rcp[z][c] = 1 / max(sqrt(U[c][c]), 1e-4)
__global__ void diag_rcp(const float* __restrict__ U, float* __restrict__ rcp,
                         size_t sU) {
    int c = blockIdx.x * 256 + threadIdx.x;
    int z = blockIdx.y;
    if (c >= LP) return;
    rcp[z*LP + c] = 1.0f / fmaxf(sqrtf(U[(size_t)z*sU + (size_t)c * (LP + 1)]), 1e-4f);
}

// Row softmax over U[p][*] fused with masking, boost, clip, bf16 round.
// One wave per row p; writes V tiles [pby][ckt][r][40] (hi only).
__global__ __launch_bounds__(256) void softmax_split(
    const float* __restrict__ Ub, const float* __restrict__ rcpb,
    const float* __restrict__ mmb, const float* __restrict__ mab,
    short* __restrict__ Vhi,
    size_t sU, size_t sV)
{
    const int z = blockIdx.y;
    const int wid = threadIdx.x >> 6, lane = threadIdx.x & 63;
    const int p = blockIdx.x * 4 + wid;
    const float* U = Ub + (size_t)z * sU + (size_t)p * LP;
    const float* rcp = rcpb + z * LP;
    const float* mm = mmb + (size_t)z * LP;
    const float maP = mab[(size_t)z * LP + p];
    const float maS = maP * 10.0f;
    float t[9][4], mv[9][4];
    float mx = -INFINITY;
    #pragma unroll
    for (int i = 0; i < 9; ++i) {
        const int c = i * 256 + lane * 4;
        float4 u4 = *(const float4*)(U + c);
        float4 r4 = *(const float4*)(rcp + c);
        float4 m4 = *(const float4*)(mm + c);
        t[i][0] = u4.x * r4.x * m4.x * maS;  mv[i][0] = m4.x;
        t[i][1] = u4.y * r4.y * m4.y * maS;  mv[i][1] = m4.y;
        t[i][2] = u4.z * r4.z * m4.z * maS;  mv[i][2] = m4.z;
        t[i][3] = u4.w * r4.w * m4.w * maS;  mv[i][3] = m4.w;
        #pragma unroll
        for (int jj = 0; jj < 4; ++jj) mx = fmaxf(mx, t[i][jj]);
    }
    #pragma unroll
    for (int off = 32; off > 0; off >>= 1) mx = fmaxf(mx, __shfl_xor(mx, off, 64));
    float sm = 0.0f;
    #pragma unroll
    for (int i = 0; i < 9; ++i)
        #pragma unroll
        for (int jj = 0; jj < 4; ++jj) sm += __expf(t[i][jj] - mx);
    #pragma unroll
    for (int off = 32; off > 0; off >>= 1) sm += __shfl_xor(sm, off, 64);
    const float rS = 1.0f / sm;
    const int pi = p / W2, pj = p - pi * W2;
    const int pby = p >> 7, pr = p & 127;
    #pragma unroll
    for (int i = 0; i < 9; ++i) {
        const int c = i * 256 + lane * 4;
        short4v h4;
        #pragma unroll
        for (int jj = 0; jj < 4; ++jj) {
            int cc = c + jj;
            float r = __expf(t[i][jj] - mx) * rS;
            int ci = cc / W2, cj = cc - ci * W2;
            if (abs(ci - pi) + abs(cj - pj) == 1) r = r + r * 0.5f;
            r = (r * mv[i][jj]) * maP;
            r = fmaxf(r, 1e-8f);
            h4[jj] = (short)f2bf(r);
        }
        size_t voff = ((size_t)(pby * 72 + (c >> 5)) * 128 + pr) * 40 + (c & 31);
        *(short4v*)(Vhi + (size_t)z * sV + voff) = h4;
    }
}

// y[z][ch][yy][xx] = 0.25 * sum over valid (ky,kx) of Z[(ch,ky,kx)][i*48+j]
__global__ void scatter_y(const float* __restrict__ Zb, float* __restrict__ yb,
                          size_t sZ, size_t sY) {
    int idx = blockIdx.x * 256 + threadIdx.x;
    int z = blockIdx.y;
    const float* Z = Zb + (size_t)z * sZ;
    int ch = idx / (H1*W1), r = idx % (H1*W1);
    int yy = r / W1, xx = r % W1;
    float s = 0.0f;
    #pragma unroll
    for (int ky = 0; ky < 4; ++ky) {
        int ny = yy + 1 - ky;
        if (ny & 1) continue;
        int i = ny >> 1;
        if ((unsigned)i >= H2) continue;
        #pragma unroll
        for (int kx = 0; kx < 4; ++kx) {
            int nx = xx + 1 - kx;
            if (nx & 1) continue;
            int j = nx >> 1;
            if ((unsigned)j >= W2) continue;
            s += Z[(size_t)(ch*16 + ky*4 + kx) * LP + i*W2 + j];
        }
    }
    yb[(size_t)z * sY + idx] = s * 0.25f;
}

// Dilated conv, IC-split 4x: block (bx = b*4*36 + g*36 + tile, by = ic chunk).
__global__ __launch_bounds__(256) void dilated_conv_part(
    const float* __restrict__ y, const float* __restrict__ w,
    float* __restrict__ part) {
    int bid = blockIdx.x;                 // b*4*36 + g*36 + tile
    int tile = bid % 36; int g = (bid / 36) % 4; int b = bid / 144;
    int c4 = blockIdx.y;                  // ic chunk: [c4*32, c4*32+32)
    int yy = (tile / 6) * 16 + (threadIdx.x >> 4);
    int xx = (tile % 6) * 16 + (threadIdx.x & 15);
    int rr = 1 << g;                      // RATES = 1,2,4,8
    const float* yb = y + ((size_t)b * CCH + c4 * 32) * (H1 * W1);
    const float* wg = w + g * 16 * CCH * 9 + c4 * 32 * 9;
    float acc[16] = {};
    #pragma unroll 2
    for (int ic = 0; ic < 32; ++ic) {
        const float* yc = yb + ic * (H1 * W1);
        #pragma unroll
        for (int t = 0; t < 9; ++t) {
            int sy = yy + rr * (t / 3 - 1), sx = xx + rr * (t % 3 - 1);
            float v = 0.0f;
            if ((unsigned)sy < H1 && (unsigned)sx < W1) v = yc[sy*W1 + sx];
            #pragma unroll
            for (int oc = 0; oc < 16; ++oc)
                acc[oc] = fmaf(v, wg[(oc*CCH + ic)*9 + t], acc[oc]);
        }
    }
    float* pb = part + (((size_t)c4 * BATCH + b) * 64 + g * 16) * (H1 * W1)
                     + yy * W1 + xx;
    #pragma unroll
    for (int oc = 0; oc < 16; ++oc)
        pb[(size_t)oc * (H1 * W1)] = acc[oc];
}

// out[b][oc64][pix] = relu(sum_c4 part[c4][b][oc64][pix] + bias[oc64])
__global__ void conv_reduce(const float* __restrict__ part,
                            const float* __restrict__ bias,
                            float* __restrict__ out) {
    int idx = blockIdx.x * 256 + threadIdx.x;     // [0, 2*64*9216)
    int pix = idx % (H1 * W1);
    int rest = idx / (H1 * W1);
    int oc64 = rest % 64, b = rest / 64;
    const size_t st = (size_t)BATCH * 64 * (H1 * W1);
    size_t o = ((size_t)b * 64 + oc64) * (H1 * W1) + pix;
    float s = part[o] + part[st + o] + part[2*st + o] + part[3*st + o];
    out[o] = fmaxf(s + bias[oc64], 0.0f);
}

extern "C" void kernel_launch(void* const* d_in, const int* in_sizes, int n_in,
                              void* d_out, int out_size, void* d_ws, size_t ws_size,
                              hipStream_t stream) {
    const float* x1       = (const float*)d_in[0];
    const float* x2       = (const float*)d_in[1];
    const float* mask     = (const float*)d_in[2];
    const float* mask_all = (const float*)d_in[3];
    const float* conv_w   = (const float*)d_in[4];
    const float* conv_b   = (const float*)d_in[5];

    // per-batch element counts
    const size_t EA = 3317760;   // shorts: 18*36*128*40
    const size_t ER = 5898240;   // shorts: 16*72*128*40
    const size_t EV = 6635520;   // shorts: 18*72*128*40
    const size_t FU = 5308416;   // floats: 2304*2304
    const size_t FZ = 4718592;   // floats: 2048*2304
    const size_t FY = 2359296;   // floats: both batches of Y

    struct Offs { size_t A0, A1, A2, U, Rh, Z, Vh, Y, MS, MA, MM, RCP, need; };
    auto mk = [&](int NZ) {
        Offs o;
        o.A0 = 0;
        o.A1 = o.A0 + (size_t)NZ * EA * 2;
        o.A2 = o.A1 + (size_t)NZ * EA * 2;
        o.U  = o.A2 + (size_t)NZ * EA * 2;
        size_t endA = o.U + (size_t)NZ * FU * 4;
        o.Rh = 0;                                // reuses A/U region (dead by then)
        o.Z  = o.Rh + (size_t)NZ * ER * 2;
        size_t endR = o.Z + (size_t)NZ * FZ * 4;
        size_t r1 = endA > endR ? endA : endR;
        o.Vh = r1;
        o.Y  = o.Vh + (size_t)NZ * EV * 2;
        o.MS = o.Y + FY * 4;
        o.MA = o.MS + 4608 * 4;
        o.MM = o.MA + 4608 * 4;
        o.RCP = o.MM + 4608 * 4;
        o.need = o.RCP + 4608 * 4;
        return o;
    };
    Offs o2 = mk(2), o1 = mk(1);
    if (ws_size < o1.need) return;               // fail loudly
    const int NZ = (ws_size >= o2.need) ? 2 : 1;
    Offs o = (NZ == 2) ? o2 : o1;

    char* base = (char*)d_ws;
    short* A0  = (short*)(base + o.A0);
    short* A1  = (short*)(base + o.A1);
    short* A2  = (short*)(base + o.A2);
    float* U   = (float*)(base + o.U);
    short* Rh  = (short*)(base + o.Rh);
    float* Z   = (float*)(base + o.Z);
    short* Vh  = (short*)(base + o.Vh);
    float* Y   = (float*)(base + o.Y);
    float* MS  = (float*)(base + o.MS);
    float* MA  = (float*)(base + o.MA);
    float* MM  = (float*)(base + o.MM);
    float* RCP = (float*)(base + o.RCP);
    // conv partials alias region-1 (A/U/R/Z all dead after last scatter_y)
    float* PART = (float*)(base + 0);

    resize_masks<<<18, 256, 0, stream>>>(mask, mask_all, MS, MA);
    compute_mm<<<18, 256, 0, stream>>>(MS, MM);

    const size_t sX2 = (size_t)CCH * LP;
    const size_t sX1 = (size_t)CCH * H1 * W1;
    const size_t sYb = (size_t)CCH * H1 * W1;

    const int nIter = (NZ == 2) ? 1 : 2;
    for (int it = 0; it < nIter; ++it) {
        const int b0 = (NZ == 2) ? 0 : it;
        im2col_split3<<<dim3(10368, NZ), 256, 0, stream>>>(
            x2 + (size_t)b0 * sX2, A0, A1, A2, sX2, EA);
        gemm1_sym3<<<dim3(171, 1, NZ), 256, 0, stream>>>(
            A0, A1, A2, U, 36, LP, EA, FU);
        diag_rcp<<<dim3(9, NZ), 256, 0, stream>>>(U, RCP, FU);
        softmax_split<<<dim3(576, NZ), 256, 0, stream>>>(
            U, RCP, MM + (size_t)b0 * LP, MA + (size_t)b0 * LP, Vh, FU, EV);
        rwt_bf16<<<dim3(18432, NZ), 256, 0, stream>>>(
            x1 + (size_t)b0 * sX1, Rh, sX1, ER);
        gemm2_bf16<<<dim3(288, 1, NZ), 256, 0, stream>>>(
            Rh, Vh, Z, 72, LP, ER, EV, FZ);
        scatter_y<<<dim3(4608, NZ), 256, 0, stream>>>(
            Z, Y + (size_t)b0 * sYb, FZ, sYb);
    }
    dilated_conv_part<<<dim3(288, 4), 256, 0, stream>>>(Y, conv_w, PART);
    conv_reduce<<<4608, 256, 0, stream>>>(PART, conv_b, (float*)d_out);
}